// Round 4
// baseline (163.269 us; speedup 1.0000x reference)
//
#include <hip/hip_runtime.h>

#define BTOT 8192
#define TT 512
#define LOG2E 1.44269504089f

__device__ __forceinline__ float rcp_f(float x) { return __builtin_amdgcn_rcpf(x); }
__device__ __forceinline__ float exp2_f(float x) { return __builtin_amdgcn_exp2f(x); }
// quad broadcasts: every lane of the quad gets lane k's value
__device__ __forceinline__ float qb0(float v) {
    return __int_as_float(__builtin_amdgcn_mov_dpp(__float_as_int(v), 0x00, 0xf, 0xf, false));
}
__device__ __forceinline__ float qb1(float v) {
    return __int_as_float(__builtin_amdgcn_mov_dpp(__float_as_int(v), 0x55, 0xf, 0xf, false));
}
__device__ __forceinline__ float qb2(float v) {
    return __int_as_float(__builtin_amdgcn_mov_dpp(__float_as_int(v), 0xAA, 0xf, 0xf, false));
}
__device__ __forceinline__ float qb3(float v) {
    return __int_as_float(__builtin_amdgcn_mov_dpp(__float_as_int(v), 0xFF, 0xf, 0xf, false));
}

__global__ __launch_bounds__(64) void lstm_kernel(
    const float* __restrict__ x,
    const float* __restrict__ W_ih,
    const float* __restrict__ W_hh,
    const float* __restrict__ b_ih,
    const float* __restrict__ b_hh,
    const float* __restrict__ fc1_w,
    const float* __restrict__ fc1_b,
    const float* __restrict__ fc2_w,
    const float* __restrict__ fc2_b,
    float* __restrict__ out)
{
    const int lane = threadIdx.x;          // one wave per block, all 64 lanes active
    const int g    = lane & 3;             // gate owned (0=i,1=f,2=g,3=o)
    const int b    = blockIdx.x * 16 + (lane >> 2);   // 16 batches per wave, exact

    // fold activation scaling (incl. log2e for raw exp2) into weights:
    //  i,f,o: acc = -z*log2e  -> sigmoid(z) =     rcp(1+exp2(acc))
    //  g    : acc = 2z*log2e  -> tanh(z)    = 1 - 2*rcp(1+exp2(acc))
    const float sc   = (g == 2) ? (2.0f * LOG2E) : (-LOG2E);
    const float selA = (g == 2) ? -2.0f :  1.0f;
    const float selB = (g == 2) ?  1.0f :  0.0f;

    // lane owns rows g*5+j (j=0..4): gate g of every hidden unit
    float wih[5][5], whh[5][5], bias[5];
    #pragma unroll
    for (int j = 0; j < 5; ++j) {
        const int row = g * 5 + j;
        #pragma unroll
        for (int i = 0; i < 5; ++i) {
            wih[j][i] = sc * W_ih[row * 5 + i];
            whh[j][i] = sc * W_hh[row * 5 + i];
        }
        bias[j] = sc * (b_ih[row] + b_hh[row]);
    }

    const float* xb = x + (size_t)b * (TT * 5);

    float hv[5] = {0.f, 0.f, 0.f, 0.f, 0.f};
    float cv[5] = {0.f, 0.f, 0.f, 0.f, 0.f};

    float4 bufA[5], bufB[5];
    #pragma unroll
    for (int i = 0; i < 5; ++i) {
        bufA[i] = *(const float4*)(xb + 0  + 4 * i);   // t = 0..3
        bufB[i] = *(const float4*)(xb + 20 + 4 * i);   // t = 4..7
    }

    auto process4 = [&](const float4* buf) {
        float xs[20];
        *(float4*)&xs[0]  = buf[0];
        *(float4*)&xs[4]  = buf[1];
        *(float4*)&xs[8]  = buf[2];
        *(float4*)&xs[12] = buf[3];
        *(float4*)&xs[16] = buf[4];

        // x-projection for 4 steps x 5 units (independent FMA chains, good ILP)
        float gx[4][5];
        #pragma unroll
        for (int s = 0; s < 4; ++s)
            #pragma unroll
            for (int j = 0; j < 5; ++j) {
                float a = bias[j];
                #pragma unroll
                for (int i = 0; i < 5; ++i) a = fmaf(wih[j][i], xs[s * 5 + i], a);
                gx[s][j] = a;
            }

        #pragma unroll
        for (int s = 0; s < 4; ++s) {
            float val[5];
            #pragma unroll
            for (int j = 0; j < 5; ++j) {
                float acc = gx[s][j];
                #pragma unroll
                for (int k = 0; k < 5; ++k) acc = fmaf(whh[j][k], hv[k], acc);
                // own-gate activation; inf-safe: rcp(inf)=0
                val[j] = fmaf(selA, rcp_f(1.0f + exp2_f(acc)), selB);
            }
            #pragma unroll
            for (int j = 0; j < 5; ++j) {
                // absolute gates via quad broadcast (no selects, no LDS)
                const float iv = qb0(val[j]);
                const float fv = qb1(val[j]);
                const float gv = qb2(val[j]);
                const float ov = qb3(val[j]);
                cv[j] = fmaf(fv, cv[j], iv * gv);
                const float ec = exp2_f(cv[j] * (2.0f * LOG2E));
                const float tc = fmaf(-2.0f, rcp_f(1.0f + ec), 1.0f);
                hv[j] = ov * tc;   // full h replicated on every lane
            }
        }
    };

    for (int t0 = 0; t0 < TT; t0 += 8) {
        process4(bufA);                                // steps t0 .. t0+3
        {
            const int tld = (t0 + 8 <= TT - 4) ? (t0 + 8) : (TT - 4);
            const float* p = xb + tld * 5;
            #pragma unroll
            for (int i = 0; i < 5; ++i) bufA[i] = *(const float4*)(p + 4 * i);
        }
        process4(bufB);                                // steps t0+4 .. t0+7
        {
            const int tld = (t0 + 12 <= TT - 4) ? (t0 + 12) : (TT - 4);
            const float* p = xb + tld * 5;
            #pragma unroll
            for (int i = 0; i < 5; ++i) bufB[i] = *(const float4*)(p + 4 * i);
        }
    }

    // h fully replicated in-register; lane 0 of each quad writes both heads
    if (g == 0) {
        float p = fc1_b[0];
        float v = fc2_b[0];
        #pragma unroll
        for (int k = 0; k < 5; ++k) {
            p = fmaf(fc1_w[k], hv[k], p);
            v = fmaf(fc2_w[k], hv[k], v);
        }
        out[b] = p;
        out[BTOT + b] = v;
    }
}

extern "C" void kernel_launch(void* const* d_in, const int* in_sizes, int n_in,
                              void* d_out, int out_size, void* d_ws, size_t ws_size,
                              hipStream_t stream) {
    const float* x     = (const float*)d_in[0];
    const float* W_ih  = (const float*)d_in[1];
    const float* W_hh  = (const float*)d_in[2];
    const float* b_ih  = (const float*)d_in[3];
    const float* b_hh  = (const float*)d_in[4];
    const float* fc1_w = (const float*)d_in[5];
    const float* fc1_b = (const float*)d_in[6];
    const float* fc2_w = (const float*)d_in[7];
    const float* fc2_b = (const float*)d_in[8];
    float* out = (float*)d_out;

    const int blocks = BTOT / 16;   // 512 one-wave blocks, 16 batches each
    lstm_kernel<<<blocks, 64, 0, stream>>>(x, W_ih, W_hh, b_ih, b_hh,
                                           fc1_w, fc1_b, fc2_w, fc2_b, out);
}

// Round 5
// 112.476 us; speedup vs baseline: 1.4516x; 1.4516x over previous
//
#include <hip/hip_runtime.h>

#define BTOT 8192
#define TT 512
#define LOG2E 1.44269504089f

__device__ __forceinline__ float rcp_f(float x) { return __builtin_amdgcn_rcpf(x); }
__device__ __forceinline__ float exp2_f(float x) { return __builtin_amdgcn_exp2f(x); }

template<int CTRL>
__device__ __forceinline__ float dpp_f(float v) {
    return __int_as_float(__builtin_amdgcn_mov_dpp(__float_as_int(v), CTRL, 0xf, 0xf, true));
}
// quad_perm broadcasts
#define QB0 0x00
#define QB1 0x55
#define QB2 0xAA
#define QB3 0xFF
// row shifts: row_shr:4 -> dst[i]=src[i-4] (valid i%16>=4); row_shl:4 -> dst[i]=src[i+4] (valid i%16<12)
#define SHL4 0x104
#define SHR4 0x114

__global__ __launch_bounds__(64) void lstm_kernel(
    const float* __restrict__ x,
    const float* __restrict__ W_ih,
    const float* __restrict__ W_hh,
    const float* __restrict__ b_ih,
    const float* __restrict__ b_hh,
    const float* __restrict__ fc1_w,
    const float* __restrict__ fc1_b,
    const float* __restrict__ fc2_w,
    const float* __restrict__ fc2_b,
    float* __restrict__ out)
{
    const int lane = threadIdx.x;            // one wave per block
    const int g    = lane & 3;               // gate (0=i,1=f,2=g,3=o)
    const int qB   = (lane >> 2) & 1;        // 0: units {0,1,2}; 1: units {3,4,pad}
    const int b    = blockIdx.x * 8 + (lane >> 3);   // 8 batches/wave

    // fold activation scaling (incl log2e) into weights:
    //  i,f,o: acc=-z*log2e -> sigmoid(z)=rcp(1+exp2(acc)); g: acc=2z*log2e -> tanh
    const float sc   = (g == 2) ? (2.0f * LOG2E) : (-LOG2E);
    const float selA = (g == 2) ? -2.0f :  1.0f;
    const float selB = (g == 2) ?  1.0f :  0.0f;

    // 3 unit-slots per lane; quad B slot 2 is an inert pad (zero weights -> c=h=0)
    float wih[3][5], whh[3][5], bias[3];
    #pragma unroll
    for (int s = 0; s < 3; ++s) {
        const int u = qB * 3 + s;
        const bool real = (u < 5);
        const int row = g * 5 + (real ? u : 0);
        #pragma unroll
        for (int i = 0; i < 5; ++i) {
            wih[s][i] = real ? sc * W_ih[row * 5 + i] : 0.0f;
            whh[s][i] = real ? sc * W_hh[row * 5 + i] : 0.0f;
        }
        bias[s] = real ? sc * (b_ih[row] + b_hh[row]) : 0.0f;
    }

    const float* xb = x + (size_t)b * (TT * 5);

    float hv[5] = {0.f, 0.f, 0.f, 0.f, 0.f};
    float cv[3] = {0.f, 0.f, 0.f};

    float4 bufA[5], bufB[5];
    #pragma unroll
    for (int i = 0; i < 5; ++i) {
        bufA[i] = *(const float4*)(xb + 0  + 4 * i);   // t = 0..3
        bufB[i] = *(const float4*)(xb + 20 + 4 * i);   // t = 4..7
    }

    auto process4 = [&](const float4* buf) {
        float xs[20];
        *(float4*)&xs[0]  = buf[0];
        *(float4*)&xs[4]  = buf[1];
        *(float4*)&xs[8]  = buf[2];
        *(float4*)&xs[12] = buf[3];
        *(float4*)&xs[16] = buf[4];

        float gx[4][3];
        #pragma unroll
        for (int s = 0; s < 4; ++s)
            #pragma unroll
            for (int j = 0; j < 3; ++j) {
                float a = bias[j];
                #pragma unroll
                for (int i = 0; i < 5; ++i) a = fmaf(wih[j][i], xs[s * 5 + i], a);
                gx[s][j] = a;
            }

        #pragma unroll
        for (int s = 0; s < 4; ++s) {
            float val[3];
            #pragma unroll
            for (int j = 0; j < 3; ++j) {
                float acc = gx[s][j];
                #pragma unroll
                for (int k = 0; k < 5; ++k) acc = fmaf(whh[j][k], hv[k], acc);
                val[j] = fmaf(selA, rcp_f(1.0f + exp2_f(acc)), selB);
            }
            float hs[3];
            #pragma unroll
            for (int j = 0; j < 3; ++j) {
                const float iv = dpp_f<QB0>(val[j]);
                const float fv = dpp_f<QB1>(val[j]);
                const float gv = dpp_f<QB2>(val[j]);
                const float ov = dpp_f<QB3>(val[j]);
                cv[j] = fmaf(fv, cv[j], iv * gv);
                const float ec = exp2_f(cv[j] * (2.0f * LOG2E));
                const float tc = fmaf(-2.0f, rcp_f(1.0f + ec), 1.0f);
                hs[j] = ov * tc;
            }
            // cross-quad h exchange (DPP row shifts, no LDS)
            const float eshl0 = dpp_f<SHL4>(hs[0]);   // quadA lanes <- quadB h3
            const float eshl1 = dpp_f<SHL4>(hs[1]);   // quadA lanes <- quadB h4
            const float eshr0 = dpp_f<SHR4>(hs[0]);   // quadB lanes <- quadA h0
            const float eshr1 = dpp_f<SHR4>(hs[1]);   // quadB lanes <- quadA h1
            const float eshr2 = dpp_f<SHR4>(hs[2]);   // quadB lanes <- quadA h2
            hv[0] = qB ? eshr0 : hs[0];
            hv[1] = qB ? eshr1 : hs[1];
            hv[2] = qB ? eshr2 : hs[2];
            hv[3] = qB ? hs[0] : eshl0;
            hv[4] = qB ? hs[1] : eshl1;
        }
    };

    for (int t0 = 0; t0 < TT; t0 += 8) {
        process4(bufA);                                // steps t0 .. t0+3
        {
            const int tld = (t0 + 8 <= TT - 4) ? (t0 + 8) : (TT - 4);
            const float* p = xb + tld * 5;
            #pragma unroll
            for (int i = 0; i < 5; ++i) bufA[i] = *(const float4*)(p + 4 * i);
        }
        process4(bufB);                                // steps t0+4 .. t0+7
        {
            const int tld = (t0 + 12 <= TT - 4) ? (t0 + 12) : (TT - 4);
            const float* p = xb + tld * 5;
            #pragma unroll
            for (int i = 0; i < 5; ++i) bufB[i] = *(const float4*)(p + 4 * i);
        }
    }

    // every lane holds the full final h in hv[]; lane 0 of each batch-octet writes
    if ((lane & 7) == 0) {
        float p = fc1_b[0];
        float v = fc2_b[0];
        #pragma unroll
        for (int k = 0; k < 5; ++k) {
            p = fmaf(fc1_w[k], hv[k], p);
            v = fmaf(fc2_w[k], hv[k], v);
        }
        out[b] = p;
        out[BTOT + b] = v;
    }
}

extern "C" void kernel_launch(void* const* d_in, const int* in_sizes, int n_in,
                              void* d_out, int out_size, void* d_ws, size_t ws_size,
                              hipStream_t stream) {
    const float* x     = (const float*)d_in[0];
    const float* W_ih  = (const float*)d_in[1];
    const float* W_hh  = (const float*)d_in[2];
    const float* b_ih  = (const float*)d_in[3];
    const float* b_hh  = (const float*)d_in[4];
    const float* fc1_w = (const float*)d_in[5];
    const float* fc1_b = (const float*)d_in[6];
    const float* fc2_w = (const float*)d_in[7];
    const float* fc2_b = (const float*)d_in[8];
    float* out = (float*)d_out;

    const int blocks = BTOT / 8;   // 1024 one-wave blocks, 8 batches each -> 1 wave/SIMD
    lstm_kernel<<<blocks, 64, 0, stream>>>(x, W_ih, W_hh, b_ih, b_hh,
                                           fc1_w, fc1_b, fc2_w, fc2_b, out);
}